// Round 7
// baseline (169.578 us; speedup 1.0000x reference)
//
#include <hip/hip_runtime.h>
#include <math.h>

// FFTConvReservoir: y = tanh(ifft(fft(u)*fft(K)).real + D*u); B=8,H=256,L=8192 fp32.
// Round 15. (a) Cooperative fusion (R14) is NOT graph-capturable -> abandoned.
// (b) Audit found R9's M3 LDS pattern was actually 4-way bank-conflicted (bank
// algebra: l2 + one of (l0,l5) unrecoverable), explaining SQ_LDS_BANK_CONFLICT
// clamped at 2^20. Fix structurally: radix-16 middle. conv middle 5 passes -> 3:
//   M1  = 16 elems @ stride 32 (spans 256..32, dif_apply<4>)
//   M2m = 16 contiguous elems: span-16 via __shfl_xor(1) + W32 twiddles (on the
//         fly from the W16 pyramid), spans 8..1 in regs, *kw, inverse, span-16 back
//   M1' = inverse of M1
// LDS ops/thread 320 -> 192. New swizzle SWc(e)=e^((e>>5)&0xF) proven EXACTLY
// 2-way (free) for all patterns by GF(2) rank: A/A' (e0^e5 collapse), M1
// (bank=t[4:0]^const), M2 (bank bijective in t[4:0]). Wave-private middle and
// 2 barriers kept. launch_bounds(512,2): LDS caps at 2 blocks/CU anyway; VGPR
// cap 128 covers the ~105-reg M2 peak (watch WRITE_SIZE for spill).
// (c) kfft 2 kernels -> 1: quadrant combine (verified kfft1 math) computed in
// registers from the K row inside the chunk-FFT kernel (verified kfft2 math).
// Lessons kept: no b64 LDS (R7), kw=(FFT(K)+D)/N folded (R6), scalar b32 LDS
// (R3), launch_bounds 2nd arg = min blocks/CU (R11/R12), no cooperative launch
// (R14), NT=512 conv skeleton (R9).

#define LL 8192
#define NT 512
#define HH 256
#define TWO_PI 6.2831853071795864f
#define CP16 0.980785280403230f  // cos(pi/16)
#define SP16 0.195090322016128f  // sin(pi/16)
#define CP8  0.92387953251129f   // cos(pi/8)
#define SP8  0.38268343236509f   // sin(pi/8)
#define CP4  0.70710678118654752f
#define SP4  0.70710678118654752f

// conv swizzle: bits[3:0] ^= e[8:5]. Exactly 2-way for all conv LDS patterns.
__device__ __forceinline__ int SWc(int e) {
    return e ^ ((e >> 5) & 0xF);
}
// kfft swizzle (2048-elem LDS): bits[4:2] ^= e[7:5]. Verified R13 (kfft2).
__device__ __forceinline__ int SW2(int e) {
    return e ^ (((e >> 5) & 7) << 2);
}
__device__ __forceinline__ float fast_tanh(float x) {
    float e = __expf(2.0f * x);
    return 1.0f - 2.0f / (e + 1.0f);
}

// Twiddle pyramid: level j at offset (1<<j)-1, length 2^j; top level chained cmul,
// lower levels by squaring.
template<int JT>
__device__ __forceinline__ void fill_pyr_cs(float c0, float s0, float Er, float Ei,
                                            float* twr, float* twi) {
    const int off = (1 << JT) - 1;
    twr[off] = c0; twi[off] = s0;
    #pragma unroll
    for (int m = 1; m < (1 << JT); ++m) {
        const float pr = twr[off + m - 1], pi = twi[off + m - 1];
        twr[off + m] = pr * Er - pi * Ei;
        twi[off + m] = pr * Ei + pi * Er;
    }
    #pragma unroll
    for (int j = JT - 1; j >= 0; --j) {
        #pragma unroll
        for (int m = 0; m < (1 << j); ++m) {
            const float a = twr[(2 << j) - 1 + m], b = twi[(2 << j) - 1 + m];
            twr[(1 << j) - 1 + m] = a * a - b * b;
            twi[(1 << j) - 1 + m] = 2.0f * a * b;
        }
    }
}
template<int JT>
__device__ __forceinline__ void fill_pyr(float ang0, float Er, float Ei,
                                         float* twr, float* twi) {
    float s, c;
    __sincosf(ang0, &s, &c);
    fill_pyr_cs<JT>(c, s, Er, Ei, twr, twi);
}

template<int R2>
__device__ __forceinline__ void dif_apply(float* xr, float* xi,
                                          const float* twr, const float* twi) {
    #pragma unroll
    for (int j = R2 - 1; j >= 0; --j) {
        #pragma unroll
        for (int q = 0; q < (1 << (R2 - 1)); ++q) {
            const int mm = q & ((1 << j) - 1);
            const int m0 = ((q >> j) << (j + 1)) | mm;
            const int m1 = m0 + (1 << j);
            const float wr = twr[(1 << j) - 1 + mm], wi = twi[(1 << j) - 1 + mm];
            const float ar = xr[m0], ai = xi[m0], br = xr[m1], bi = xi[m1];
            xr[m0] = ar + br; xi[m0] = ai + bi;
            const float dr = ar - br, di = ai - bi;
            xr[m1] = dr * wr - di * wi;
            xi[m1] = dr * wi + di * wr;
        }
    }
}
template<int R2>
__device__ __forceinline__ void dit_apply(float* xr, float* xi,
                                          const float* twr, const float* twi) {
    #pragma unroll
    for (int j = 0; j < R2; ++j) {
        #pragma unroll
        for (int q = 0; q < (1 << (R2 - 1)); ++q) {
            const int mm = q & ((1 << j) - 1);
            const int m0 = ((q >> j) << (j + 1)) | mm;
            const int m1 = m0 + (1 << j);
            const float wr = twr[(1 << j) - 1 + mm], wi = twi[(1 << j) - 1 + mm];
            const float br = xr[m1] * wr - xi[m1] * wi;
            const float bi = xr[m1] * wi + xi[m1] * wr;
            const float ar = xr[m0], ai = xi[m0];
            xr[m0] = ar + br; xi[m0] = ai + bi;
            xr[m1] = ar - br; xi[m1] = ai - bi;
        }
    }
}
// dit with conjugated twiddles (reuse forward pyramid; negation is free VOP3 mod).
template<int R2>
__device__ __forceinline__ void dit_apply_c(float* xr, float* xi,
                                            const float* twr, const float* twi) {
    #pragma unroll
    for (int j = 0; j < R2; ++j) {
        #pragma unroll
        for (int q = 0; q < (1 << (R2 - 1)); ++q) {
            const int mm = q & ((1 << j) - 1);
            const int m0 = ((q >> j) << (j + 1)) | mm;
            const int m1 = m0 + (1 << j);
            const float wr = twr[(1 << j) - 1 + mm], wi = -twi[(1 << j) - 1 + mm];
            const float br = xr[m1] * wr - xi[m1] * wi;
            const float bi = xr[m1] * wi + xi[m1] * wr;
            const float ar = xr[m0], ai = xi[m0];
            xr[m0] = ar + br; xi[m0] = ai + bi;
            xr[m1] = ar - br; xi[m1] = ai - bi;
        }
    }
}

// ---------------- conv: NT=512, radix-16 middle ----------------
// Chunk ownership: wave wv owns chunks 2wv, 2wv+1 (wave-private between barriers).
// Within the wave: t = lane&31, ch = 2wv + (lane>>5). M1: elems ch*512 + t + 32j.
// M2m: elems ch*512 + 16t + j (contiguous); span-16 partner = lane^1 (same wave).

__global__ __launch_bounds__(NT, 2) void conv_kernel(const float* __restrict__ u,
                                                     const float2* __restrict__ Kf,
                                                     float* __restrict__ out) {
    __shared__ float re[LL];
    __shared__ float im[LL];
    const int tid = threadIdx.x;
    const int h = blockIdx.x & (HH - 1);
    const int pr_ = blockIdx.x >> 8;        // batch pair 0..3
    const size_t off0 = ((size_t)(pr_ * 2) * HH + h) * LL;
    const size_t off1 = off0 + (size_t)HH * LL;
    const float* u0 = u + off0;
    const float* u1 = u + off1;

    float xr[16], xi[16];
    #pragma unroll
    for (int m = 0; m < 16; ++m) {
        xr[m] = u0[tid + (m << 9)];
        xi[m] = u1[tid + (m << 9)];
    }
    // Pass A: spans 4096..512, then scatter (z = u0 + i*u1).
    {
        float twr[15], twi[15];
        fill_pyr<3>(-(TWO_PI / 8192.0f) * (float)tid, CP8, -SP8, twr, twi);
        dif_apply<4>(xr, xi, twr, twi);
        #pragma unroll
        for (int m = 0; m < 16; ++m) {
            const int p = SWc(tid + (m << 9));
            re[p] = xr[m]; im[p] = xi[m];
        }
    }
    __syncthreads();

    const int lane = tid & 63, wv = tid >> 6;
    const int t = lane & 31;
    const int ch = (wv << 1) + (lane >> 5);
    const int cb = ch << 9;
    const int par = lane & 1;
    const float s = par ? -1.0f : 1.0f;

    // kw prefetch: 16 contiguous complex per thread (8x dwordx4), consumed in M2m.
    float kwr[16], kwi[16];
    {
        const float4* kp = (const float4*)(Kf + (size_t)h * LL + cb + (t << 4));
        #pragma unroll
        for (int jj = 0; jj < 8; ++jj) {
            const float4 v = kp[jj];
            kwr[2 * jj]     = v.x; kwi[2 * jj]     = v.y;
            kwr[2 * jj + 1] = v.z; kwi[2 * jj + 1] = v.w;
        }
    }

    // ---- wave-private middle ----
    // M1 fwd: spans 256/128/64/32.
    {
        float twr[15], twi[15];
        fill_pyr<3>(-(TWO_PI / 512.0f) * (float)t, CP8, -SP8, twr, twi);
        const int base = cb + t;
        float ar[16], ai[16];
        #pragma unroll
        for (int j = 0; j < 16; ++j) {
            const int p = SWc(base + (j << 5));
            ar[j] = re[p]; ai[j] = im[p];
        }
        dif_apply<4>(ar, ai, twr, twi);
        #pragma unroll
        for (int j = 0; j < 16; ++j) {
            const int p = SWc(base + (j << 5));
            re[p] = ar[j]; im[p] = ai[j];
        }
    }
    // M2 merged: span-16 (shfl) -> spans 8..1 -> *kw -> inv 1..8 -> span-16 (shfl).
    {
        float twd_r[15], twd_i[15];               // constant W16 pyramid
        fill_pyr_cs<3>(1.0f, 0.0f, CP8, -SP8, twd_r, twd_i);
        const int base2 = cb + (t << 4);
        float yr[16], yi[16];
        #pragma unroll
        for (int j = 0; j < 16; ++j) {
            const int p = SWc(base2 + j);
            yr[j] = re[p]; yi[j] = im[p];
        }
        // forward span-16: even lane holds lows (out = a+b), odd holds highs
        // (out = (a-b) * W32^j). W32^j: even j -> W16^(j/2) = twd[7+j/2];
        // odd j -> (CP16,-SP16) * W16^(j/2).
        #pragma unroll
        for (int j = 0; j < 16; ++j) {
            const float vr = __shfl_xor(yr[j], 1);
            const float vi = __shfl_xor(yi[j], 1);
            const float tr = fmaf(yr[j], s, vr);
            const float ti = fmaf(yi[j], s, vi);
            const float br = twd_r[7 + (j >> 1)], bi = twd_i[7 + (j >> 1)];
            float wr_, wi_;
            if (j & 1) { wr_ = CP16 * br + SP16 * bi; wi_ = CP16 * bi - SP16 * br; }
            else       { wr_ = br;                    wi_ = bi; }
            wr_ = par ? wr_ : 1.0f;
            wi_ = par ? wi_ : 0.0f;
            yr[j] = tr * wr_ - ti * wi_;
            yi[j] = tr * wi_ + ti * wr_;
        }
        dif_apply<4>(yr, yi, twd_r, twd_i);       // spans 8,4,2,1
        #pragma unroll
        for (int j = 0; j < 16; ++j) {
            const float a = yr[j], bb = yi[j];
            yr[j] = a * kwr[j] - bb * kwi[j];
            yi[j] = a * kwi[j] + bb * kwr[j];
        }
        dit_apply_c<4>(yr, yi, twd_r, twd_i);     // spans 1,2,4,8 (conj)
        // inverse span-16: odd pre-multiplies by conj(W32^j), then exchange:
        // even: out = own + recv; odd: out = recv - own.
        #pragma unroll
        for (int j = 0; j < 16; ++j) {
            const float br = twd_r[7 + (j >> 1)], bi = twd_i[7 + (j >> 1)];
            float wr_, wi_;
            if (j & 1) { wr_ = CP16 * br + SP16 * bi; wi_ = CP16 * bi - SP16 * br; }
            else       { wr_ = br;                    wi_ = bi; }
            wr_ = par ? wr_ : 1.0f;
            wi_ = par ? wi_ : 0.0f;
            const float tr = yr[j] * wr_ + yi[j] * wi_;   // y * conj(w)
            const float ti = yi[j] * wr_ - yr[j] * wi_;
            const float vr = __shfl_xor(tr, 1);
            const float vi = __shfl_xor(ti, 1);
            yr[j] = fmaf(tr, s, vr);
            yi[j] = fmaf(ti, s, vi);
        }
        #pragma unroll
        for (int j = 0; j < 16; ++j) {
            const int p = SWc(base2 + j);
            re[p] = yr[j]; im[p] = yi[j];
        }
    }
    // M1' inv: spans 32/64/128/256.
    {
        float twr[15], twi[15];
        fill_pyr<3>((TWO_PI / 512.0f) * (float)t, CP8, SP8, twr, twi);
        const int base = cb + t;
        float ar[16], ai[16];
        #pragma unroll
        for (int j = 0; j < 16; ++j) {
            const int p = SWc(base + (j << 5));
            ar[j] = re[p]; ai[j] = im[p];
        }
        dit_apply<4>(ar, ai, twr, twi);
        #pragma unroll
        for (int j = 0; j < 16; ++j) {
            const int p = SWc(base + (j << 5));
            re[p] = ar[j]; im[p] = ai[j];
        }
    }
    __syncthreads();

    // Pass A' (spans 512..4096) + epilogue (skip/norm folded into kw).
    {
        float twr[15], twi[15];
        #pragma unroll
        for (int m = 0; m < 16; ++m) {
            const int p = SWc(tid + (m << 9));
            xr[m] = re[p]; xi[m] = im[p];
        }
        fill_pyr<3>((TWO_PI / 8192.0f) * (float)tid, CP8, SP8, twr, twi);
        dit_apply<4>(xr, xi, twr, twi);
    }
    float* o0 = out + off0;
    float* o1 = out + off1;
    #pragma unroll
    for (int m = 0; m < 16; ++m) {
        const int n = tid + (m << 9);
        o0[n] = fast_tanh(xr[m]);
        o1[n] = fast_tanh(xi[m]);
    }
}

// ---------------- kfft: one kernel, quadrant combine + 2048-pt chunk FFT --------
// Block (h = b>>2, cq = b&3), NT=256, 16 KB LDS, 1 barrier. Quadrant combine
// (kfft1 math, verbatim R13) in registers from the K row; reg pass spans
// 1024/512/256; M1 spans 128/64/32; M2 spans 16/8/4 (same-wave handoff, no
// barrier); spans 2/1 via shfl; fold kw=(X+D[h])/N; store natural order.
__global__ __launch_bounds__(256) void kfftF_kernel(const float* __restrict__ K,
                                                    const float* __restrict__ D,
                                                    float2* __restrict__ Kf) {
    __shared__ float re[2048];
    __shared__ float im[2048];
    const int b = blockIdx.x;
    const int h = b >> 2, cq = b & 3;
    const int tid = threadIdx.x;
    const float* Kr = K + (size_t)h * LL;

    float xr[8], xi[8];
    #pragma unroll
    for (int j = 0; j < 8; ++j) {
        const int m = tid + (j << 8);                  // [0,2048)
        const float A  = Kr[m];
        const float Bv = Kr[m + 2048];
        const float C  = Kr[m + 4096];
        const float E  = Kr[m + 6144];
        if (cq == 0) {
            xr[j] = A + C + Bv + E; xi[j] = 0.0f;
        } else {
            float sn, cs;
            __sincosf(-(TWO_PI / 8192.0f) * (float)m, &sn, &cs);
            if (cq == 1) {
                const float dif = A + C - Bv - E;
                const float c2 = cs * cs - sn * sn, s2 = 2.0f * cs * sn;
                xr[j] = dif * c2; xi[j] = dif * s2;
            } else {
                const float p_ = A - C, q_ = Bv - E;
                if (cq == 2) {
                    xr[j] = p_ * cs + q_ * sn; xi[j] = p_ * sn - q_ * cs;
                } else {
                    const float c2 = cs * cs - sn * sn, s2 = 2.0f * cs * sn;
                    const float c3 = cs * c2 - sn * s2, s3 = cs * s2 + sn * c2;
                    xr[j] = p_ * c3 - q_ * s3; xi[j] = p_ * s3 + q_ * c3;
                }
            }
        }
    }
    {
        float twr[7], twi[7];
        fill_pyr<2>(-(TWO_PI / 2048.0f) * (float)tid, CP4, -SP4, twr, twi);
        dif_apply<3>(xr, xi, twr, twi);
    }
    #pragma unroll
    for (int j = 0; j < 8; ++j) {
        const int p = SW2(tid + (j << 8));
        re[p] = xr[j]; im[p] = xi[j];
    }
    __syncthreads();
    {
        const int t_ = tid & 31, sub = tid >> 5;
        float twr[7], twi[7];
        fill_pyr<2>(-(TWO_PI / 256.0f) * (float)t_, CP4, -SP4, twr, twi);
        const int be = (sub << 8) + t_;
        float ar[8], ai[8];
        #pragma unroll
        for (int j = 0; j < 8; ++j) {
            const int p = SW2(be + (j << 5));
            ar[j] = re[p]; ai[j] = im[p];
        }
        dif_apply<3>(ar, ai, twr, twi);
        #pragma unroll
        for (int j = 0; j < 8; ++j) {
            const int p = SW2(be + (j << 5));
            re[p] = ar[j]; im[p] = ai[j];
        }
    }
    // M1 -> M2 handoff same-wave (verified R13): no barrier.
    {
        const int blk = tid >> 2, r = tid & 3;
        float twr[7], twi[7];
        fill_pyr<2>(-(TWO_PI / 32.0f) * (float)r, CP4, -SP4, twr, twi);
        const int eb = (blk << 5) + r;
        float yr[8], yi[8];
        #pragma unroll
        for (int j = 0; j < 8; ++j) {
            const int p = SW2(eb + (j << 2));
            yr[j] = re[p]; yi[j] = im[p];
        }
        dif_apply<3>(yr, yi, twr, twi);
        const float s2_ = (r < 2) ? 1.0f : -1.0f;
        #pragma unroll
        for (int j = 0; j < 8; ++j) {
            const float vr = __shfl_xor(yr[j], 2);
            const float vi = __shfl_xor(yi[j], 2);
            const float tr = fmaf(yr[j], s2_, vr);
            const float ti = fmaf(yi[j], s2_, vi);
            yr[j] = (r == 3) ? ti : tr;
            yi[j] = (r == 3) ? -tr : ti;
        }
        const float s1_ = (r & 1) ? -1.0f : 1.0f;
        #pragma unroll
        for (int j = 0; j < 8; ++j) {
            const float vr = __shfl_xor(yr[j], 1);
            const float vi = __shfl_xor(yi[j], 1);
            yr[j] = fmaf(yr[j], s1_, vr);
            yi[j] = fmaf(yi[j], s1_, vi);
        }
        const float dh = D[h];
        const float invN = 1.0f / (float)LL;
        float2* baseo = Kf + (size_t)h * LL + (cq << 11);
        #pragma unroll
        for (int j = 0; j < 8; ++j) {
            baseo[eb + (j << 2)] = make_float2((yr[j] + dh) * invN, yi[j] * invN);
        }
    }
}

extern "C" void kernel_launch(void* const* d_in, const int* in_sizes, int n_in,
                              void* d_out, int out_size, void* d_ws, size_t ws_size,
                              hipStream_t stream) {
    const float* u = (const float*)d_in[0];   // (8, 256, 8192)
    const float* K = (const float*)d_in[1];   // (256, 8192)
    const float* D = (const float*)d_in[2];   // (256,)
    float* out = (float*)d_out;               // (8, 256, 8192)
    float2* Kf = (float2*)d_ws;               // 256 * 8192 float2 = 16 MB

    kfftF_kernel<<<dim3(4 * HH), dim3(256), 0, stream>>>(K, D, Kf);
    conv_kernel<<<dim3(4 * HH), dim3(NT), 0, stream>>>(u, Kf, out);
}

// Round 8
// 148.781 us; speedup vs baseline: 1.1398x; 1.1398x over previous
//
#include <hip/hip_runtime.h>
#include <math.h>

// FFTConvReservoir: y = tanh(ifft(fft(u)*fft(K)).real + D*u); B=8,H=256,L=8192 fp32.
// Round 16: best-verified pieces + surgical swizzle fix.
// - conv: verbatim R13 structure (NT=512, 5-pass wave-private middle, 2 barriers,
//   VGPR 60, 51us verified). R15 proved the radix-16 middle regresses (71us: lost
//   2-round ILP, VGPR 84) even with 0 bank conflicts -> conflicts are minor, ILP
//   is major. Keep structure; fix ONLY the swizzle: R9's SW left M3 4-way.
//   SW6(e)=e^((e>>4)&0x18)^((e>>5)&7) is GF(2)-verified EXACTLY 2-way (free) for
//   ALL conv patterns: A/A' (l0^l5 collapse), M1 (l0^l5), M2 (b0/r1 pair),
//   M3 (l1^l5). Triangular high->low bits -> bijective.
// - kfft: R15's single fused kernel (quadrant combine + 2048-pt chunk FFT),
//   verified pass; 2 launches total.
// Non-conv residual ~95-100us is invariant to kfft impl & launch count
// (R8/R9/R12/R13/R15) -> fixed overhead; conv is the only lever.
// Lessons kept: no b64 LDS (R7), kw=(FFT(K)+D)/N folded (R6), scalar b32 LDS
// (R3), launch_bounds 2nd arg = min blocks/CU (R11/R12), no cooperative launch
// (R14), NT=512 conv skeleton (R9), no radix-16 middle (R15).

#define LL 8192
#define NT 512
#define HH 256
#define TWO_PI 6.2831853071795864f
#define CP8  0.92387953251129f    // cos(pi/8)
#define SP8  0.38268343236509f    // sin(pi/8)
#define CP4  0.70710678118654752f // cos(pi/4)
#define SP4  0.70710678118654752f // sin(pi/4)

// conv swizzle SW6: bits[4:3] ^= e[8:7], bits[2:0] ^= e[7:5]. Exactly 2-way for
// A/A' (e=m<<9|tid), M1 (e=c<<9|j<<6|lane), M2 (e=c<<9|b<<6|j<<3|r),
// M3 (e=c<<9|lane<<3|j). Bijective (strictly high->low XOR).
__device__ __forceinline__ int SW(int e) {
    return e ^ ((e >> 4) & 0x18) ^ ((e >> 5) & 0x07);
}
// kfft swizzle (2048-elem LDS): bits[4:2] ^= e[7:5]. Verified R13 (kfft2).
__device__ __forceinline__ int SW2(int e) {
    return e ^ (((e >> 5) & 7) << 2);
}
__device__ __forceinline__ float fast_tanh(float x) {
    float e = __expf(2.0f * x);
    return 1.0f - 2.0f / (e + 1.0f);
}

// Twiddle pyramid: level j at offset (1<<j)-1, length 2^j; top level chained cmul,
// lower levels by squaring.
template<int JT>
__device__ __forceinline__ void fill_pyr_cs(float c0, float s0, float Er, float Ei,
                                            float* twr, float* twi) {
    const int off = (1 << JT) - 1;
    twr[off] = c0; twi[off] = s0;
    #pragma unroll
    for (int m = 1; m < (1 << JT); ++m) {
        const float pr = twr[off + m - 1], pi = twi[off + m - 1];
        twr[off + m] = pr * Er - pi * Ei;
        twi[off + m] = pr * Ei + pi * Er;
    }
    #pragma unroll
    for (int j = JT - 1; j >= 0; --j) {
        #pragma unroll
        for (int m = 0; m < (1 << j); ++m) {
            const float a = twr[(2 << j) - 1 + m], b = twi[(2 << j) - 1 + m];
            twr[(1 << j) - 1 + m] = a * a - b * b;
            twi[(1 << j) - 1 + m] = 2.0f * a * b;
        }
    }
}
template<int JT>
__device__ __forceinline__ void fill_pyr(float ang0, float Er, float Ei,
                                         float* twr, float* twi) {
    float s, c;
    __sincosf(ang0, &s, &c);
    fill_pyr_cs<JT>(c, s, Er, Ei, twr, twi);
}

template<int R2>
__device__ __forceinline__ void dif_apply(float* xr, float* xi,
                                          const float* twr, const float* twi) {
    #pragma unroll
    for (int j = R2 - 1; j >= 0; --j) {
        #pragma unroll
        for (int q = 0; q < (1 << (R2 - 1)); ++q) {
            const int mm = q & ((1 << j) - 1);
            const int m0 = ((q >> j) << (j + 1)) | mm;
            const int m1 = m0 + (1 << j);
            const float wr = twr[(1 << j) - 1 + mm], wi = twi[(1 << j) - 1 + mm];
            const float ar = xr[m0], ai = xi[m0], br = xr[m1], bi = xi[m1];
            xr[m0] = ar + br; xi[m0] = ai + bi;
            const float dr = ar - br, di = ai - bi;
            xr[m1] = dr * wr - di * wi;
            xi[m1] = dr * wi + di * wr;
        }
    }
}
template<int R2>
__device__ __forceinline__ void dit_apply(float* xr, float* xi,
                                          const float* twr, const float* twi) {
    #pragma unroll
    for (int j = 0; j < R2; ++j) {
        #pragma unroll
        for (int q = 0; q < (1 << (R2 - 1)); ++q) {
            const int mm = q & ((1 << j) - 1);
            const int m0 = ((q >> j) << (j + 1)) | mm;
            const int m1 = m0 + (1 << j);
            const float wr = twr[(1 << j) - 1 + mm], wi = twi[(1 << j) - 1 + mm];
            const float br = xr[m1] * wr - xi[m1] * wi;
            const float bi = xr[m1] * wi + xi[m1] * wr;
            const float ar = xr[m0], ai = xi[m0];
            xr[m0] = ar + br; xi[m0] = ai + bi;
            xr[m1] = ar - br; xi[m1] = ai - bi;
        }
    }
}

// ---------------- conv building blocks (R9/R13 structure, NT=512) ----------

__device__ __forceinline__ void fwd_A(float* xr, float* xi, int tid,
                                      float* re, float* im) {
    float twr[15], twi[15];
    fill_pyr<3>(-(TWO_PI / 8192.0f) * (float)tid, CP8, -SP8, twr, twi);
    dif_apply<4>(xr, xi, twr, twi);
    #pragma unroll
    for (int m = 0; m < 16; ++m) {
        const int p = SW(tid + (m << 9));
        re[p] = xr[m]; im[p] = xi[m];
    }
}

template<bool INV>
__device__ __forceinline__ void mid_M1(float* re, float* im, int lane, int wv) {
    float twr[7], twi[7];
    const float sgn = INV ? 1.0f : -1.0f;
    fill_pyr<2>(sgn * (TWO_PI / 512.0f) * (float)lane, CP4, sgn * SP4, twr, twi);
    #pragma unroll
    for (int r = 0; r < 2; ++r) {
        const int base = (((wv << 1) | r) << 9) + lane;
        float ar[8], ai[8];
        #pragma unroll
        for (int j = 0; j < 8; ++j) {
            const int p = SW(base + (j << 6));
            ar[j] = re[p]; ai[j] = im[p];
        }
        if (INV) dit_apply<3>(ar, ai, twr, twi);
        else     dif_apply<3>(ar, ai, twr, twi);
        #pragma unroll
        for (int j = 0; j < 8; ++j) {
            const int p = SW(base + (j << 6));
            re[p] = ar[j]; im[p] = ai[j];
        }
    }
}

template<bool INV>
__device__ __forceinline__ void mid_M2(float* re, float* im, int lane, int wv) {
    float twr[7], twi[7];
    const float sgn = INV ? 1.0f : -1.0f;
    fill_pyr<2>(sgn * (TWO_PI / 64.0f) * (float)(lane & 7), CP4, sgn * SP4, twr, twi);
    const int sub = ((lane >> 3) << 6) + (lane & 7);
    #pragma unroll
    for (int r = 0; r < 2; ++r) {
        const int base = (((wv << 1) | r) << 9) + sub;
        float ar[8], ai[8];
        #pragma unroll
        for (int j = 0; j < 8; ++j) {
            const int p = SW(base + (j << 3));
            ar[j] = re[p]; ai[j] = im[p];
        }
        if (INV) dit_apply<3>(ar, ai, twr, twi);
        else     dif_apply<3>(ar, ai, twr, twi);
        #pragma unroll
        for (int j = 0; j < 8; ++j) {
            const int p = SW(base + (j << 3));
            re[p] = ar[j]; im[p] = ai[j];
        }
    }
}

__global__ __launch_bounds__(NT, 4) void conv_kernel(const float* __restrict__ u,
                                                     const float2* __restrict__ Kf,
                                                     float* __restrict__ out) {
    __shared__ float re[LL];
    __shared__ float im[LL];
    const int tid = threadIdx.x;
    const int h = blockIdx.x & (HH - 1);
    const int pr_ = blockIdx.x >> 8;        // batch pair 0..3
    const size_t off0 = ((size_t)(pr_ * 2) * HH + h) * LL;
    const size_t off1 = off0 + (size_t)HH * LL;
    const float* u0 = u + off0;
    const float* u1 = u + off1;

    float xr[16], xi[16];
    #pragma unroll
    for (int m = 0; m < 16; ++m) {
        xr[m] = u0[tid + (m << 9)];
        xi[m] = u1[tid + (m << 9)];
    }
    fwd_A(xr, xi, tid, re, im);       // z = u0 + i*u1
    __syncthreads();

    const int lane = tid & 63, wv = tid >> 6;
    const int c0 = (wv << 1);               // wave's chunks: c0, c0+1

    // kw prefetch for both rounds (dwordx4, per-lane contiguous), consumed in M3
    // a full M1+M2 later.
    float kwr[2][8], kwi[2][8];
    #pragma unroll
    for (int r = 0; r < 2; ++r) {
        const int eb = ((c0 | r) << 9) + (lane << 3);
        const float4* kp = (const float4*)(Kf + (size_t)h * LL + eb);
        #pragma unroll
        for (int jj = 0; jj < 4; ++jj) {
            const float4 v = kp[jj];
            kwr[r][2 * jj] = v.x;     kwi[r][2 * jj] = v.y;
            kwr[r][2 * jj + 1] = v.z; kwi[r][2 * jj + 1] = v.w;
        }
    }

    // ---- wave-private middle: no __syncthreads until pass A' ----
    mid_M1<false>(re, im, lane, wv);
    mid_M2<false>(re, im, lane, wv);

    // Merged M3: spans 4/2/1 fwd, *kw, inverse 1/2/4. Constant pyramids.
    {
        float twd_r[7], twd_i[7], twu_r[7], twu_i[7];
        fill_pyr_cs<2>(1.0f, 0.0f, CP4, -SP4, twd_r, twd_i);
        fill_pyr_cs<2>(1.0f, 0.0f, CP4, SP4, twu_r, twu_i);
        #pragma unroll
        for (int r = 0; r < 2; ++r) {
            const int eb = ((c0 | r) << 9) + (lane << 3);
            float yr[8], yi[8];
            #pragma unroll
            for (int j = 0; j < 8; ++j) {
                const int p = SW(eb + j);
                yr[j] = re[p]; yi[j] = im[p];
            }
            dif_apply<3>(yr, yi, twd_r, twd_i);
            #pragma unroll
            for (int j = 0; j < 8; ++j) {
                const float a = yr[j], b = yi[j];
                yr[j] = a * kwr[r][j] - b * kwi[r][j];
                yi[j] = a * kwi[r][j] + b * kwr[r][j];
            }
            dit_apply<3>(yr, yi, twu_r, twu_i);
            #pragma unroll
            for (int j = 0; j < 8; ++j) {
                const int p = SW(eb + j);
                re[p] = yr[j]; im[p] = yi[j];
            }
        }
    }

    mid_M2<true>(re, im, lane, wv);
    mid_M1<true>(re, im, lane, wv);
    __syncthreads();

    // Inv pass A' (spans 512..4096) + epilogue (skip/norm folded into kw).
    {
        float twr[15], twi[15];
        #pragma unroll
        for (int m = 0; m < 16; ++m) {
            const int p = SW(tid + (m << 9));
            xr[m] = re[p]; xi[m] = im[p];
        }
        fill_pyr<3>((TWO_PI / 8192.0f) * (float)tid, CP8, SP8, twr, twi);
        dit_apply<4>(xr, xi, twr, twi);
    }
    float* o0 = out + off0;
    float* o1 = out + off1;
    #pragma unroll
    for (int m = 0; m < 16; ++m) {
        const int n = tid + (m << 9);
        o0[n] = fast_tanh(xr[m]);
        o1[n] = fast_tanh(xi[m]);
    }
}

// ---------------- kfft: one kernel, quadrant combine + 2048-pt chunk FFT --------
// Block (h = b>>2, cq = b&3), NT=256, 16 KB LDS, 1 barrier. Quadrant combine
// (kfft1 math) in registers from the K row; reg pass spans 1024/512/256; M1
// spans 128/64/32; M2 spans 16/8/4 (same-wave handoff, no barrier); spans 2/1
// via shfl; fold kw=(X+D[h])/N; store natural order. Verified R15.
__global__ __launch_bounds__(256) void kfftF_kernel(const float* __restrict__ K,
                                                    const float* __restrict__ D,
                                                    float2* __restrict__ Kf) {
    __shared__ float re[2048];
    __shared__ float im[2048];
    const int b = blockIdx.x;
    const int h = b >> 2, cq = b & 3;
    const int tid = threadIdx.x;
    const float* Kr = K + (size_t)h * LL;

    float xr[8], xi[8];
    #pragma unroll
    for (int j = 0; j < 8; ++j) {
        const int m = tid + (j << 8);                  // [0,2048)
        const float A  = Kr[m];
        const float Bv = Kr[m + 2048];
        const float C  = Kr[m + 4096];
        const float E  = Kr[m + 6144];
        if (cq == 0) {
            xr[j] = A + C + Bv + E; xi[j] = 0.0f;
        } else {
            float sn, cs;
            __sincosf(-(TWO_PI / 8192.0f) * (float)m, &sn, &cs);
            if (cq == 1) {
                const float dif = A + C - Bv - E;
                const float c2 = cs * cs - sn * sn, s2 = 2.0f * cs * sn;
                xr[j] = dif * c2; xi[j] = dif * s2;
            } else {
                const float p_ = A - C, q_ = Bv - E;
                if (cq == 2) {
                    xr[j] = p_ * cs + q_ * sn; xi[j] = p_ * sn - q_ * cs;
                } else {
                    const float c2 = cs * cs - sn * sn, s2 = 2.0f * cs * sn;
                    const float c3 = cs * c2 - sn * s2, s3 = cs * s2 + sn * c2;
                    xr[j] = p_ * c3 - q_ * s3; xi[j] = p_ * s3 + q_ * c3;
                }
            }
        }
    }
    {
        float twr[7], twi[7];
        fill_pyr<2>(-(TWO_PI / 2048.0f) * (float)tid, CP4, -SP4, twr, twi);
        dif_apply<3>(xr, xi, twr, twi);
    }
    #pragma unroll
    for (int j = 0; j < 8; ++j) {
        const int p = SW2(tid + (j << 8));
        re[p] = xr[j]; im[p] = xi[j];
    }
    __syncthreads();
    {
        const int t_ = tid & 31, sub = tid >> 5;
        float twr[7], twi[7];
        fill_pyr<2>(-(TWO_PI / 256.0f) * (float)t_, CP4, -SP4, twr, twi);
        const int be = (sub << 8) + t_;
        float ar[8], ai[8];
        #pragma unroll
        for (int j = 0; j < 8; ++j) {
            const int p = SW2(be + (j << 5));
            ar[j] = re[p]; ai[j] = im[p];
        }
        dif_apply<3>(ar, ai, twr, twi);
        #pragma unroll
        for (int j = 0; j < 8; ++j) {
            const int p = SW2(be + (j << 5));
            re[p] = ar[j]; im[p] = ai[j];
        }
    }
    // M1 -> M2 handoff same-wave (verified R13): no barrier.
    {
        const int blk = tid >> 2, r = tid & 3;
        float twr[7], twi[7];
        fill_pyr<2>(-(TWO_PI / 32.0f) * (float)r, CP4, -SP4, twr, twi);
        const int eb = (blk << 5) + r;
        float yr[8], yi[8];
        #pragma unroll
        for (int j = 0; j < 8; ++j) {
            const int p = SW2(eb + (j << 2));
            yr[j] = re[p]; yi[j] = im[p];
        }
        dif_apply<3>(yr, yi, twr, twi);
        const float s2_ = (r < 2) ? 1.0f : -1.0f;
        #pragma unroll
        for (int j = 0; j < 8; ++j) {
            const float vr = __shfl_xor(yr[j], 2);
            const float vi = __shfl_xor(yi[j], 2);
            const float tr = fmaf(yr[j], s2_, vr);
            const float ti = fmaf(yi[j], s2_, vi);
            yr[j] = (r == 3) ? ti : tr;
            yi[j] = (r == 3) ? -tr : ti;
        }
        const float s1_ = (r & 1) ? -1.0f : 1.0f;
        #pragma unroll
        for (int j = 0; j < 8; ++j) {
            const float vr = __shfl_xor(yr[j], 1);
            const float vi = __shfl_xor(yi[j], 1);
            yr[j] = fmaf(yr[j], s1_, vr);
            yi[j] = fmaf(yi[j], s1_, vi);
        }
        const float dh = D[h];
        const float invN = 1.0f / (float)LL;
        float2* baseo = Kf + (size_t)h * LL + (cq << 11);
        #pragma unroll
        for (int j = 0; j < 8; ++j) {
            baseo[eb + (j << 2)] = make_float2((yr[j] + dh) * invN, yi[j] * invN);
        }
    }
}

extern "C" void kernel_launch(void* const* d_in, const int* in_sizes, int n_in,
                              void* d_out, int out_size, void* d_ws, size_t ws_size,
                              hipStream_t stream) {
    const float* u = (const float*)d_in[0];   // (8, 256, 8192)
    const float* K = (const float*)d_in[1];   // (256, 8192)
    const float* D = (const float*)d_in[2];   // (256,)
    float* out = (float*)d_out;               // (8, 256, 8192)
    float2* Kf = (float2*)d_ws;               // 256 * 8192 float2 = 16 MB

    kfftF_kernel<<<dim3(4 * HH), dim3(256), 0, stream>>>(K, D, Kf);
    conv_kernel<<<dim3(4 * HH), dim3(NT), 0, stream>>>(u, Kf, out);
}